// Round 12
// baseline (2518.079 us; speedup 1.0000x reference)
//
#include <hip/hip_runtime.h>
#include <hip/hip_fp16.h>

// LSTM: B=256, S=4096, D=64, H=128 (4H=512 gate cols [i|f|g|o]), K=192=[h;x].
// One batch element per block (256 blocks = 1/CU), 256 threads = 4 waves
// (1 wave/SIMD). z = [h;x] @ [Wh;Wi] via v_mfma_f32_16x16x32_f16, A rows 0+4
// carry the batch row (lanes 0-31 own one unit's gates, v_cndmask combine).
// PIPELINE (new vs R11): x-part MFMAs (kk4,5) for step s+1 are issued during
// step s AFTER the h-part, into accX; step s+1's first h-MFMA (kk0) takes
// accX as C-in. The matrix pipe stays busy through the combine/barrier tail.
//   per-SIMD per step: 32 h-MFMA (critical) + 16 x-MFMA (overlap) = 48.
// LDS rings (audited, one barrier/step):
//   Hbuf[2]: h_{s+1} written @s into [ (s+1)&1 ], read @s+1.  (disjoint parity)
//   Xbuf[2]: x_{s+2} written @s into [ s&1 ],     read @s+1 (as x-frag for
//            step s+2: Xbuf[(s+2)&1]=Xbuf[s&1]) — write@s, barrier, read@s+1.
//   Prologue stages Xbuf[0]=x_0, Xbuf[1]=x_1; extra barrier after prologue
//   x-MFMAs protects Xbuf[0] from step-0's x_2 write (WAR).
// B-frags/A-frags share the (lgrp,j)->k map (proven R9-R11). Activations and
// c/h formulas identical to all passing rounds (absmax 4.88e-4).

#define LSTM_B 256
#define LSTM_S 4096
#define LSTM_D 64
#define LSTM_H 128
#define LSTM_G 512

typedef _Float16 f16x8 __attribute__((ext_vector_type(8)));
typedef float f32x4 __attribute__((ext_vector_type(4)));

__device__ __forceinline__ float sigm(float z) {
  return __builtin_amdgcn_rcpf(1.0f + __builtin_amdgcn_exp2f(-1.44269504f * z));
}
__device__ __forceinline__ float tanh_(float z) {
  return 1.0f - 2.0f * __builtin_amdgcn_rcpf(1.0f + __builtin_amdgcn_exp2f(2.88539008f * z));
}

__global__ __launch_bounds__(256, 1)
void lstm_mfma_kernel(const float* __restrict__ x,
                      const float* __restrict__ Wi,
                      const float* __restrict__ Wh,
                      const float* __restrict__ bh,
                      const float* __restrict__ Wo,
                      const float* __restrict__ bo,
                      float* __restrict__ out) {
  const int t    = threadIdx.x;      // 0..255
  const int lane = t & 63;
  const int w    = t >> 6;           // wave 0..3
  const int b    = blockIdx.x;
  const int lmod = lane & 15;        // row (A) / col (B) index within tile
  const int lgrp = lane >> 4;        // k-group 0..3

  __shared__ __align__(16) _Float16 Hbuf[2][LSTM_H];  // h rings (256B each)
  __shared__ __align__(16) _Float16 Xbuf[2][LSTM_D];  // x rings (128B each)
  __shared__ __align__(16) _Float16 Zr[8];            // zero region (16B)
  __shared__ float R[LSTM_H];                         // final reduce

  // ---- stage B fragments: nt = 2g+hh -> cols n = 128g + 32w + 16hh + lmod
  // elem j of Bf[nt][kk] = W[k][n], k = 32*kk + 8*lgrp + j (same map as A)
  f16x8 Bf[8][6];
  #pragma unroll
  for (int g = 0; g < 4; ++g) {
    #pragma unroll
    for (int hh = 0; hh < 2; ++hh) {
      const int nt = 2 * g + hh;
      const int n = 128 * g + 32 * w + 16 * hh + lmod;
      #pragma unroll
      for (int kk = 0; kk < 6; ++kk) {
        union { f16x8 v; _Float16 e[8]; } uB;
        #pragma unroll
        for (int j = 0; j < 8; ++j) {
          const int k = 32 * kk + 8 * lgrp + j;
          const float val = (k < LSTM_H) ? Wh[(size_t)k * LSTM_G + n]
                                         : Wi[(size_t)(k - LSTM_H) * LSTM_G + n];
          uB.e[j] = (_Float16)val;
        }
        Bf[nt][kk] = uB.v;
      }
    }
  }

  // biases for this thread's unit (lanes<32: u = 32w + (lane&31))
  const int ul = 32 * w + (lane & 31);
  const float bb0 = bh[ul];
  const float bb1 = bh[LSTM_H + ul];
  const float bb2 = bh[2 * LSTM_H + ul];
  const float bb3 = bh[3 * LSTM_H + ul];

  const float* xb = x + (size_t)b * (LSTM_S * LSTM_D);

  // x reg pipeline: at loop top of step s, xA = x_{s+2} (to write), xB = x_{s+3}
  float xA = 0.f, xB = 0.f;
  if (w == 3) {
    xA = xb[2 * LSTM_D + lane];
    xB = xb[3 * LSTM_D + lane];
  }
  // init: h_0 = 0, Xbuf[0] = x_0, Xbuf[1] = x_1, zero region
  if (t < LSTM_H) Hbuf[0][t] = (_Float16)0.0f;
  if (w == 1) Xbuf[0][lane] = (_Float16)xb[lane];
  if (w == 2) Xbuf[1][lane] = (_Float16)xb[LSTM_D + lane];
  if (t < 8) Zr[t] = (_Float16)0.0f;

  const bool areal = (lmod == 0) || (lmod == 4);
  float c = 0.f, hval = 0.f;
  __syncthreads();

  // ---- prologue: x-part of z_0 from Xbuf[0] ----
  f32x4 accX[8];
  {
    const char* axB = areal ? ((const char*)&Xbuf[0][0] + 16 * lgrp)
                            : (const char*)&Zr[0];
    const int axS = areal ? 64 : 0;
    f16x8 Ax0 = *(const f16x8*)(axB);
    f16x8 Ax1 = *(const f16x8*)(axB + axS);
    #pragma unroll
    for (int n = 0; n < 8; ++n) {
      accX[n] = __builtin_amdgcn_mfma_f32_16x16x32_f16(
          Ax0, Bf[n][4], (f32x4){0.f, 0.f, 0.f, 0.f}, 0, 0, 0);
      accX[n] = __builtin_amdgcn_mfma_f32_16x16x32_f16(Ax1, Bf[n][5], accX[n], 0, 0, 0);
    }
  }
  __syncthreads();   // protect Xbuf[0] (read above) from step-0's x_2 write

  for (int s = 0; s < LSTM_S; ++s) {
    const int rp = s & 1;              // h read parity; also x-write parity
    const int wp = rp ^ 1;             // h write parity; x-read parity (s+1)

    // global prefetch x_{s+4}
    float xnext = 0.f;
    if (w == 3) {
      int si = s + 4; if (si > LSTM_S - 1) si = LSTM_S - 1;
      xnext = xb[(size_t)si * LSTM_D + lane];
    }

    // A-frag reads: h_s (4 frags) and x_{s+1} (2 frags)
    const char* ahB = areal ? ((const char*)&Hbuf[rp][0] + 16 * lgrp)
                            : (const char*)&Zr[0];
    const int ahS = areal ? 64 : 0;
    f16x8 Ah0 = *(const f16x8*)(ahB);
    f16x8 Ah1 = *(const f16x8*)(ahB + 1 * ahS);
    f16x8 Ah2 = *(const f16x8*)(ahB + 2 * ahS);
    f16x8 Ah3 = *(const f16x8*)(ahB + 3 * ahS);
    const char* axB = areal ? ((const char*)&Xbuf[wp][0] + 16 * lgrp)
                            : (const char*)&Zr[0];
    const int axS = areal ? 64 : 0;
    f16x8 Ax0 = *(const f16x8*)(axB);
    f16x8 Ax1 = *(const f16x8*)(axB + axS);

    // ---- h-part MFMAs (critical path); C-in = accX from step s-1 ----
    f32x4 accH[8];
    #pragma unroll
    for (int n = 0; n < 8; ++n)
      accH[n] = __builtin_amdgcn_mfma_f32_16x16x32_f16(Ah0, Bf[n][0], accX[n], 0, 0, 0);
    #pragma unroll
    for (int n = 0; n < 8; ++n)
      accH[n] = __builtin_amdgcn_mfma_f32_16x16x32_f16(Ah1, Bf[n][1], accH[n], 0, 0, 0);
    #pragma unroll
    for (int n = 0; n < 8; ++n)
      accH[n] = __builtin_amdgcn_mfma_f32_16x16x32_f16(Ah2, Bf[n][2], accH[n], 0, 0, 0);
    #pragma unroll
    for (int n = 0; n < 8; ++n)
      accH[n] = __builtin_amdgcn_mfma_f32_16x16x32_f16(Ah3, Bf[n][3], accH[n], 0, 0, 0);
    __builtin_amdgcn_sched_barrier(0);

    // ---- x-part MFMAs for step s+1 (overlap the tail) ----
    #pragma unroll
    for (int n = 0; n < 8; ++n)
      accX[n] = __builtin_amdgcn_mfma_f32_16x16x32_f16(
          Ax0, Bf[n][4], (f32x4){0.f, 0.f, 0.f, 0.f}, 0, 0, 0);
    #pragma unroll
    for (int n = 0; n < 8; ++n)
      accX[n] = __builtin_amdgcn_mfma_f32_16x16x32_f16(Ax1, Bf[n][5], accX[n], 0, 0, 0);

    // ---- x ring write: x_{s+2} -> Xbuf[rp] ----
    if (w == 3) {
      Xbuf[rp][lane] = (_Float16)xA;
      xA = xB;
      xB = xnext;
    }

    // ---- in-register gate combine on lanes 0-31 ----
    {
      const bool hsel = (lane & 16) != 0;
      const float zi = (hsel ? accH[1][0] : accH[0][0]) + bb0;
      const float zf = (hsel ? accH[3][0] : accH[2][0]) + bb1;
      const float zg = (hsel ? accH[5][0] : accH[4][0]) + bb2;
      const float zo = (hsel ? accH[7][0] : accH[6][0]) + bb3;
      const float iv = sigm(zi);
      const float fv = sigm(zf);
      const float gv = tanh_(zg);
      const float ov = sigm(zo);
      c = fv * c + iv * gv;
      hval = ov * tanh_(c);
      if (lane < 32) Hbuf[wp][ul] = (_Float16)hval;   // h_{s+1}
    }
    __syncthreads();                   // single barrier per step
  }

  // ---- output: out[b] = h_last @ Wo + bo ----
  if (lane < 32) R[ul] = hval * Wo[ul];
  __syncthreads();
  if (t < 64) {
    float v = R[t] + R[t + 64];
    #pragma unroll
    for (int off = 32; off; off >>= 1) v += __shfl_down(v, off);
    if (t == 0) out[b] = v + bo[0];
  }
}

extern "C" void kernel_launch(void* const* d_in, const int* in_sizes, int n_in,
                              void* d_out, int out_size, void* d_ws, size_t ws_size,
                              hipStream_t stream) {
  const float* x  = (const float*)d_in[0];
  const float* Wi = (const float*)d_in[1];
  const float* Wh = (const float*)d_in[2];
  const float* bh = (const float*)d_in[3];
  const float* Wo = (const float*)d_in[4];
  const float* bo = (const float*)d_in[5];
  float* out = (float*)d_out;

  lstm_mfma_kernel<<<LSTM_B, 256, 0, stream>>>(x, Wi, Wh, bh, Wo, bo, out);
}

// Round 13
// 2365.062 us; speedup vs baseline: 1.0647x; 1.0647x over previous
//
#include <hip/hip_runtime.h>
#include <hip/hip_fp16.h>

// LSTM: B=256, S=4096, D=64, H=128 (4H=512 gate cols [i|f|g|o]), K=192=[h;x].
// One batch element per block (256 blocks = 1/CU), 256 threads = 4 waves
// (1 wave/SIMD). z = [h;x] @ [Wh;Wi] via v_mfma_f32_16x16x32_f16, A rows 0+4
// carry the batch row (lanes 0-31 own one unit's gates, v_cndmask combine).
// Schedule (fixes R12's in-order-issue mistake):
//   1. ds_read Ah0-3 (h_s), Ax0-1 (x_{s+1})
//   2. 32 h-MFMAs as 16 depth-2 chains: accA[n] (kk0 C-in=accX, kk1),
//      accB[n] (kk2, kk3)       [R11's ILP structure]
//   3. INTERLEAVED region, 8 mini-blocks: {2 x-MFMAs (for s+1's accX);
//      sched_barrier; one combine slice; sched_barrier} — matrix-pipe issue
//      stalls absorb the combine's VALU/trans chain instead of serializing.
//   4. h/x ring writes, one barrier.
// LDS rings audited (R12): Hbuf parity disjoint; Xbuf write@s read@s+1;
// prologue barrier protects Xbuf[0] WAR. A/B share the (lgrp,j)->k map.
// Activation/c/h formulas identical to all passing rounds (absmax 4.88e-4).

#define LSTM_B 256
#define LSTM_S 4096
#define LSTM_D 64
#define LSTM_H 128
#define LSTM_G 512

typedef _Float16 f16x8 __attribute__((ext_vector_type(8)));
typedef float f32x4 __attribute__((ext_vector_type(4)));

#define SBAR() __builtin_amdgcn_sched_barrier(0)

__device__ __forceinline__ float sigm(float z) {
  return __builtin_amdgcn_rcpf(1.0f + __builtin_amdgcn_exp2f(-1.44269504f * z));
}
__device__ __forceinline__ float tanh_(float z) {
  return 1.0f - 2.0f * __builtin_amdgcn_rcpf(1.0f + __builtin_amdgcn_exp2f(2.88539008f * z));
}

__global__ __launch_bounds__(256, 1)
void lstm_mfma_kernel(const float* __restrict__ x,
                      const float* __restrict__ Wi,
                      const float* __restrict__ Wh,
                      const float* __restrict__ bh,
                      const float* __restrict__ Wo,
                      const float* __restrict__ bo,
                      float* __restrict__ out) {
  const int t    = threadIdx.x;      // 0..255
  const int lane = t & 63;
  const int w    = t >> 6;           // wave 0..3
  const int b    = blockIdx.x;
  const int lmod = lane & 15;        // row (A) / col (B) index within tile
  const int lgrp = lane >> 4;        // k-group 0..3

  __shared__ __align__(16) _Float16 Hbuf[2][LSTM_H];  // h rings
  __shared__ __align__(16) _Float16 Xbuf[2][LSTM_D];  // x rings
  __shared__ __align__(16) _Float16 Zr[8];            // zero region (16B)
  __shared__ float R[LSTM_H];                         // final reduce

  // ---- stage B fragments: nt = 2g+hh -> cols n = 128g + 32w + 16hh + lmod
  f16x8 Bf[8][6];
  #pragma unroll
  for (int g = 0; g < 4; ++g) {
    #pragma unroll
    for (int hh = 0; hh < 2; ++hh) {
      const int nt = 2 * g + hh;
      const int n = 128 * g + 32 * w + 16 * hh + lmod;
      #pragma unroll
      for (int kk = 0; kk < 6; ++kk) {
        union { f16x8 v; _Float16 e[8]; } uB;
        #pragma unroll
        for (int j = 0; j < 8; ++j) {
          const int k = 32 * kk + 8 * lgrp + j;
          const float val = (k < LSTM_H) ? Wh[(size_t)k * LSTM_G + n]
                                         : Wi[(size_t)(k - LSTM_H) * LSTM_G + n];
          uB.e[j] = (_Float16)val;
        }
        Bf[nt][kk] = uB.v;
      }
    }
  }

  const int ul = 32 * w + (lane & 31);
  const float bb0 = bh[ul];
  const float bb1 = bh[LSTM_H + ul];
  const float bb2 = bh[2 * LSTM_H + ul];
  const float bb3 = bh[3 * LSTM_H + ul];

  const float* xb = x + (size_t)b * (LSTM_S * LSTM_D);

  // x reg pipeline: at loop top of step s, xA = x_{s+2} (to write), xB = x_{s+3}
  float xA = 0.f, xB = 0.f;
  if (w == 3) {
    xA = xb[2 * LSTM_D + lane];
    xB = xb[3 * LSTM_D + lane];
  }
  if (t < LSTM_H) Hbuf[0][t] = (_Float16)0.0f;
  if (w == 1) Xbuf[0][lane] = (_Float16)xb[lane];
  if (w == 2) Xbuf[1][lane] = (_Float16)xb[LSTM_D + lane];
  if (t < 8) Zr[t] = (_Float16)0.0f;

  const bool areal = (lmod == 0) || (lmod == 4);
  float c = 0.f, hval = 0.f;
  __syncthreads();

  // ---- prologue: accX = x-part of z_0 from Xbuf[0] ----
  f32x4 accX[8];
  {
    const char* axB = areal ? ((const char*)&Xbuf[0][0] + 16 * lgrp)
                            : (const char*)&Zr[0];
    const int axS = areal ? 64 : 0;
    f16x8 Ax0 = *(const f16x8*)(axB);
    f16x8 Ax1 = *(const f16x8*)(axB + axS);
    #pragma unroll
    for (int n = 0; n < 8; ++n) {
      accX[n] = __builtin_amdgcn_mfma_f32_16x16x32_f16(
          Ax0, Bf[n][4], (f32x4){0.f, 0.f, 0.f, 0.f}, 0, 0, 0);
      accX[n] = __builtin_amdgcn_mfma_f32_16x16x32_f16(Ax1, Bf[n][5], accX[n], 0, 0, 0);
    }
  }
  __syncthreads();   // protect Xbuf[0] (read above) from step-0's x_2 write

  for (int s = 0; s < LSTM_S; ++s) {
    const int rp = s & 1;              // h read parity; x-write parity
    const int wp = rp ^ 1;             // h write parity; x-read parity

    float xnext = 0.f;
    if (w == 3) {
      int si = s + 4; if (si > LSTM_S - 1) si = LSTM_S - 1;
      xnext = xb[(size_t)si * LSTM_D + lane];
    }

    // ---- ds_reads: h_s and x_{s+1} fragments ----
    const char* ahB = areal ? ((const char*)&Hbuf[rp][0] + 16 * lgrp)
                            : (const char*)&Zr[0];
    const int ahS = areal ? 64 : 0;
    f16x8 Ah0 = *(const f16x8*)(ahB);
    f16x8 Ah1 = *(const f16x8*)(ahB + 1 * ahS);
    f16x8 Ah2 = *(const f16x8*)(ahB + 2 * ahS);
    f16x8 Ah3 = *(const f16x8*)(ahB + 3 * ahS);
    const char* axB = areal ? ((const char*)&Xbuf[wp][0] + 16 * lgrp)
                            : (const char*)&Zr[0];
    const int axS = areal ? 64 : 0;
    f16x8 Ax0 = *(const f16x8*)(axB);
    f16x8 Ax1 = *(const f16x8*)(axB + axS);

    // ---- h-part: 16 depth-2 chains; accA takes accX as C-in ----
    f32x4 accA[8], accB[8];
    #pragma unroll
    for (int n = 0; n < 8; ++n)
      accA[n] = __builtin_amdgcn_mfma_f32_16x16x32_f16(Ah0, Bf[n][0], accX[n], 0, 0, 0);
    #pragma unroll
    for (int n = 0; n < 8; ++n)
      accB[n] = __builtin_amdgcn_mfma_f32_16x16x32_f16(
          Ah2, Bf[n][2], (f32x4){0.f, 0.f, 0.f, 0.f}, 0, 0, 0);
    #pragma unroll
    for (int n = 0; n < 8; ++n)
      accA[n] = __builtin_amdgcn_mfma_f32_16x16x32_f16(Ah1, Bf[n][1], accA[n], 0, 0, 0);
    #pragma unroll
    for (int n = 0; n < 8; ++n)
      accB[n] = __builtin_amdgcn_mfma_f32_16x16x32_f16(Ah3, Bf[n][3], accB[n], 0, 0, 0);
    SBAR();

    // ---- interleaved region: x-MFMAs (for s+1) ∥ combine slices ----
    const bool hsel = (lane & 16) != 0;
    float zi, zf, zg, zo, iv, fv, gv, ov;

    // mb0: kk4 n=0,1 | zi
    accX[0] = __builtin_amdgcn_mfma_f32_16x16x32_f16(Ax0, Bf[0][4], (f32x4){0.f,0.f,0.f,0.f}, 0, 0, 0);
    accX[1] = __builtin_amdgcn_mfma_f32_16x16x32_f16(Ax0, Bf[1][4], (f32x4){0.f,0.f,0.f,0.f}, 0, 0, 0);
    SBAR();
    zi = (hsel ? accA[1][0] + accB[1][0] : accA[0][0] + accB[0][0]) + bb0;
    SBAR();
    // mb1: kk4 n=2,3 | zf
    accX[2] = __builtin_amdgcn_mfma_f32_16x16x32_f16(Ax0, Bf[2][4], (f32x4){0.f,0.f,0.f,0.f}, 0, 0, 0);
    accX[3] = __builtin_amdgcn_mfma_f32_16x16x32_f16(Ax0, Bf[3][4], (f32x4){0.f,0.f,0.f,0.f}, 0, 0, 0);
    SBAR();
    zf = (hsel ? accA[3][0] + accB[3][0] : accA[2][0] + accB[2][0]) + bb1;
    SBAR();
    // mb2: kk4 n=4,5 | iv
    accX[4] = __builtin_amdgcn_mfma_f32_16x16x32_f16(Ax0, Bf[4][4], (f32x4){0.f,0.f,0.f,0.f}, 0, 0, 0);
    accX[5] = __builtin_amdgcn_mfma_f32_16x16x32_f16(Ax0, Bf[5][4], (f32x4){0.f,0.f,0.f,0.f}, 0, 0, 0);
    SBAR();
    iv = sigm(zi);
    SBAR();
    // mb3: kk4 n=6,7 | fv
    accX[6] = __builtin_amdgcn_mfma_f32_16x16x32_f16(Ax0, Bf[6][4], (f32x4){0.f,0.f,0.f,0.f}, 0, 0, 0);
    accX[7] = __builtin_amdgcn_mfma_f32_16x16x32_f16(Ax0, Bf[7][4], (f32x4){0.f,0.f,0.f,0.f}, 0, 0, 0);
    SBAR();
    fv = sigm(zf);
    SBAR();
    // mb4: kk5 n=0,1 | zg, zo
    accX[0] = __builtin_amdgcn_mfma_f32_16x16x32_f16(Ax1, Bf[0][5], accX[0], 0, 0, 0);
    accX[1] = __builtin_amdgcn_mfma_f32_16x16x32_f16(Ax1, Bf[1][5], accX[1], 0, 0, 0);
    SBAR();
    zg = (hsel ? accA[5][0] + accB[5][0] : accA[4][0] + accB[4][0]) + bb2;
    zo = (hsel ? accA[7][0] + accB[7][0] : accA[6][0] + accB[6][0]) + bb3;
    SBAR();
    // mb5: kk5 n=2,3 | gv
    accX[2] = __builtin_amdgcn_mfma_f32_16x16x32_f16(Ax1, Bf[2][5], accX[2], 0, 0, 0);
    accX[3] = __builtin_amdgcn_mfma_f32_16x16x32_f16(Ax1, Bf[3][5], accX[3], 0, 0, 0);
    SBAR();
    gv = tanh_(zg);
    SBAR();
    // mb6: kk5 n=4,5 | ov, c
    accX[4] = __builtin_amdgcn_mfma_f32_16x16x32_f16(Ax1, Bf[4][5], accX[4], 0, 0, 0);
    accX[5] = __builtin_amdgcn_mfma_f32_16x16x32_f16(Ax1, Bf[5][5], accX[5], 0, 0, 0);
    SBAR();
    ov = sigm(zo);
    c = fv * c + iv * gv;
    SBAR();
    // mb7: kk5 n=6,7 | h, ring writes
    accX[6] = __builtin_amdgcn_mfma_f32_16x16x32_f16(Ax1, Bf[6][5], accX[6], 0, 0, 0);
    accX[7] = __builtin_amdgcn_mfma_f32_16x16x32_f16(Ax1, Bf[7][5], accX[7], 0, 0, 0);
    SBAR();
    hval = ov * tanh_(c);
    if (lane < 32) Hbuf[wp][ul] = (_Float16)hval;   // h_{s+1}
    if (w == 3) {
      Xbuf[rp][lane] = (_Float16)xA;                // x_{s+2}
      xA = xB;
      xB = xnext;
    }
    __syncthreads();                   // single barrier per step
  }

  // ---- output: out[b] = h_last @ Wo + bo ----
  if (lane < 32) R[ul] = hval * Wo[ul];
  __syncthreads();
  if (t < 64) {
    float v = R[t] + R[t + 64];
    #pragma unroll
    for (int off = 32; off; off >>= 1) v += __shfl_down(v, off);
    if (t == 0) out[b] = v + bo[0];
  }
}

extern "C" void kernel_launch(void* const* d_in, const int* in_sizes, int n_in,
                              void* d_out, int out_size, void* d_ws, size_t ws_size,
                              hipStream_t stream) {
  const float* x  = (const float*)d_in[0];
  const float* Wi = (const float*)d_in[1];
  const float* Wh = (const float*)d_in[2];
  const float* bh = (const float*)d_in[3];
  const float* Wo = (const float*)d_in[4];
  const float* bo = (const float*)d_in[5];
  float* out = (float*)d_out;

  lstm_mfma_kernel<<<LSTM_B, 256, 0, stream>>>(x, Wi, Wh, bh, Wo, bo, out);
}

// Round 14
// 2216.113 us; speedup vs baseline: 1.1363x; 1.0672x over previous
//
#include <hip/hip_runtime.h>
#include <hip/hip_fp16.h>

// LSTM: B=256, S=4096, D=64, H=128 (4H=512 gate cols [i|f|g|o]), K=192=[h;x].
// One batch element per block (256 blocks = 1/CU), 256 threads = 4 waves
// (1 wave/SIMD). z = [h;x] @ [Wh;Wi] via v_mfma_f32_16x16x32_f16, A rows 0+4
// carry the batch row (lanes 0-31 own one unit's gates).
// Schedule per step (fixes R12/R13's tail serialization):
//   1. issue ds_read Ah (h_s) + ds_read next-x frags (x_{s+2})
//   2. 16 x-MFMAs from REGISTER x-frags (x_{s+1}, read last step) -> accOUT;
//      first MFMA C-in = ZQ (persistent zero quad: no per-step zero movs).
//      These 256 issue-cycles cover the Ah ds_read latency.
//   3. 32 h-MFMAs: 8 chains depth 4, C-in = accIN (x-part of z_s) [R12 assoc]
//   4. combine (lanes 0-31), h/x ring writes, ONE barrier.
// s-loop unrolled by 2: accP/accQ and X0/X1 frag regs ping-pong (no copies);
// ring parities hardcoded. Ring audit: Hbuf[P] read@s, write@s->P^1 (RAW
// across barrier). Xbuf[P] frag-read@s (x_{s+2}, written @s-1), write@s ->
// Xbuf[P^1] = x_{s+3} (WAR vs @s-1 frag-read protected by barrier lgkmcnt(0)
// drain; RAW to @s+1 across barrier).
// Activation/c/h formulas identical to all passing rounds (absmax 4.88e-4).

#define LSTM_B 256
#define LSTM_S 4096
#define LSTM_D 64
#define LSTM_H 128
#define LSTM_G 512

typedef _Float16 f16x8 __attribute__((ext_vector_type(8)));
typedef float f32x4 __attribute__((ext_vector_type(4)));

__device__ __forceinline__ float sigm(float z) {
  return __builtin_amdgcn_rcpf(1.0f + __builtin_amdgcn_exp2f(-1.44269504f * z));
}
__device__ __forceinline__ float tanh_(float z) {
  return 1.0f - 2.0f * __builtin_amdgcn_rcpf(1.0f + __builtin_amdgcn_exp2f(2.88539008f * z));
}

__global__ __launch_bounds__(256, 1)
void lstm_mfma_kernel(const float* __restrict__ x,
                      const float* __restrict__ Wi,
                      const float* __restrict__ Wh,
                      const float* __restrict__ bh,
                      const float* __restrict__ Wo,
                      const float* __restrict__ bo,
                      float* __restrict__ out) {
  const int t    = threadIdx.x;      // 0..255
  const int lane = t & 63;
  const int w    = t >> 6;           // wave 0..3
  const int b    = blockIdx.x;
  const int lmod = lane & 15;        // row (A) / col (B) index within tile
  const int lgrp = lane >> 4;        // k-group 0..3

  __shared__ __align__(16) _Float16 Hbuf[2][LSTM_H];  // h ring
  __shared__ __align__(16) _Float16 Xbuf[2][LSTM_D];  // x ring (lead 2)
  __shared__ __align__(16) _Float16 Zr[8];            // zero region (16B)
  __shared__ float R[LSTM_H];                         // final reduce

  // ---- stage B fragments: nt = 2g+hh -> cols n = 128g + 32w + 16hh + lmod
  // elem j of Bf[nt][kk] = W[k][n], k = 32*kk + 8*lgrp + j (same map as A)
  f16x8 Bf[8][6];
  #pragma unroll
  for (int g = 0; g < 4; ++g) {
    #pragma unroll
    for (int hh = 0; hh < 2; ++hh) {
      const int nt = 2 * g + hh;
      const int n = 128 * g + 32 * w + 16 * hh + lmod;
      #pragma unroll
      for (int kk = 0; kk < 6; ++kk) {
        union { f16x8 v; _Float16 e[8]; } uB;
        #pragma unroll
        for (int j = 0; j < 8; ++j) {
          const int k = 32 * kk + 8 * lgrp + j;
          const float val = (k < LSTM_H) ? Wh[(size_t)k * LSTM_G + n]
                                         : Wi[(size_t)(k - LSTM_H) * LSTM_G + n];
          uB.e[j] = (_Float16)val;
        }
        Bf[nt][kk] = uB.v;
      }
    }
  }

  const int ul = 32 * w + (lane & 31);
  const float bb0 = bh[ul];
  const float bb1 = bh[LSTM_H + ul];
  const float bb2 = bh[2 * LSTM_H + ul];
  const float bb3 = bh[3 * LSTM_H + ul];

  const float* xb = x + (size_t)b * (LSTM_S * LSTM_D);
  const bool areal = (lmod == 0) || (lmod == 4);

  // persistent zero quad: C-in of the first x-MFMA; NEVER written again.
  const f32x4 ZQ = {0.f, 0.f, 0.f, 0.f};

  // ---- prologue ----
  // stage x_0 -> Xbuf[0], x_1 -> Xbuf[1], h_0 = 0
  if (t < LSTM_H) Hbuf[0][t] = (_Float16)0.0f;
  if (w == 1) Xbuf[0][lane] = (_Float16)xb[lane];
  if (w == 2) Xbuf[1][lane] = (_Float16)xb[LSTM_D + lane];
  if (t < 8) Zr[t] = (_Float16)0.0f;
  __syncthreads();

  // frags of x_0 (temp) and x_1 (loop-carried X0a/X0b)
  f16x8 X0a, X0b, X1a, X1b;
  f32x4 accP[8], accQ[8];
  {
    const char* a0 = areal ? ((const char*)&Xbuf[0][0] + 16 * lgrp)
                           : (const char*)&Zr[0];
    const int s0 = areal ? 64 : 0;
    f16x8 T0 = *(const f16x8*)(a0);
    f16x8 T1 = *(const f16x8*)(a0 + s0);
    const char* a1 = areal ? ((const char*)&Xbuf[1][0] + 16 * lgrp)
                           : (const char*)&Zr[0];
    X0a = *(const f16x8*)(a1);
    X0b = *(const f16x8*)(a1 + s0);
    #pragma unroll
    for (int n = 0; n < 8; ++n) {
      accP[n] = __builtin_amdgcn_mfma_f32_16x16x32_f16(T0, Bf[n][4], ZQ, 0, 0, 0);
      accP[n] = __builtin_amdgcn_mfma_f32_16x16x32_f16(T1, Bf[n][5], accP[n], 0, 0, 0);
    }
  }
  __syncthreads();                  // Xbuf[0] frags consumed; safe to rewrite
  if (w == 1) Xbuf[0][lane] = (_Float16)xb[2 * LSTM_D + lane];   // x_2
  // x reg pipeline: loop-top invariant xA = x_{s+3}, xB = x_{s+4}
  float xA = 0.f, xB = 0.f;
  if (w == 3) {
    xA = xb[3 * LSTM_D + lane];
    xB = xb[4 * LSTM_D + lane];
  }
  float c = 0.f, hval = 0.f;
  __syncthreads();

  // one LSTM step. P: parity (s&1). ACCIN: x-part of z_s (consumed as C-in);
  // ACCOUT: x-part of z_{s+1} (produced). XC*: frags of x_{s+1} (registers).
  // XN*: frags of x_{s+2} (read this step from Xbuf[P]).
  #define STEPB(P, ACCIN, ACCOUT, XC0, XC1, XN0, XN1)                          \
  {                                                                            \
    float xn = 0.f;                                                            \
    if (w == 3) {                                                              \
      int si = s + 5; if (si > LSTM_S - 1) si = LSTM_S - 1;                    \
      xn = xb[(size_t)si * LSTM_D + lane];                                     \
    }                                                                          \
    const char* ahB = areal ? ((const char*)&Hbuf[P][0] + 16 * lgrp)           \
                            : (const char*)&Zr[0];                             \
    const int ahS = areal ? 64 : 0;                                            \
    f16x8 Ah0 = *(const f16x8*)(ahB);                                          \
    f16x8 Ah1 = *(const f16x8*)(ahB + 1 * ahS);                                \
    f16x8 Ah2 = *(const f16x8*)(ahB + 2 * ahS);                                \
    f16x8 Ah3 = *(const f16x8*)(ahB + 3 * ahS);                                \
    const char* axB = areal ? ((const char*)&Xbuf[P][0] + 16 * lgrp)           \
                            : (const char*)&Zr[0];                             \
    XN0 = *(const f16x8*)(axB);                                                \
    XN1 = *(const f16x8*)(axB + ahS);                                          \
    __builtin_amdgcn_sched_barrier(0);                                         \
    _Pragma("unroll")                                                          \
    for (int n = 0; n < 8; ++n)                                                \
      ACCOUT[n] = __builtin_amdgcn_mfma_f32_16x16x32_f16(XC0, Bf[n][4], ZQ, 0, 0, 0); \
    _Pragma("unroll")                                                          \
    for (int n = 0; n < 8; ++n)                                                \
      ACCOUT[n] = __builtin_amdgcn_mfma_f32_16x16x32_f16(XC1, Bf[n][5], ACCOUT[n], 0, 0, 0); \
    __builtin_amdgcn_sched_barrier(0);                                         \
    _Pragma("unroll")                                                          \
    for (int n = 0; n < 8; ++n)                                                \
      ACCIN[n] = __builtin_amdgcn_mfma_f32_16x16x32_f16(Ah0, Bf[n][0], ACCIN[n], 0, 0, 0); \
    _Pragma("unroll")                                                          \
    for (int n = 0; n < 8; ++n)                                                \
      ACCIN[n] = __builtin_amdgcn_mfma_f32_16x16x32_f16(Ah1, Bf[n][1], ACCIN[n], 0, 0, 0); \
    _Pragma("unroll")                                                          \
    for (int n = 0; n < 8; ++n)                                                \
      ACCIN[n] = __builtin_amdgcn_mfma_f32_16x16x32_f16(Ah2, Bf[n][2], ACCIN[n], 0, 0, 0); \
    _Pragma("unroll")                                                          \
    for (int n = 0; n < 8; ++n)                                                \
      ACCIN[n] = __builtin_amdgcn_mfma_f32_16x16x32_f16(Ah3, Bf[n][3], ACCIN[n], 0, 0, 0); \
    {                                                                          \
      const bool hsel = (lane & 16) != 0;                                      \
      const float zi = (hsel ? ACCIN[1][0] : ACCIN[0][0]) + bb0;               \
      const float zf = (hsel ? ACCIN[3][0] : ACCIN[2][0]) + bb1;               \
      const float zg = (hsel ? ACCIN[5][0] : ACCIN[4][0]) + bb2;               \
      const float zo = (hsel ? ACCIN[7][0] : ACCIN[6][0]) + bb3;               \
      const float iv = sigm(zi);                                               \
      const float fv = sigm(zf);                                               \
      const float gv = tanh_(zg);                                              \
      const float ov = sigm(zo);                                               \
      c = fv * c + iv * gv;                                                    \
      hval = ov * tanh_(c);                                                    \
      if (lane < 32) Hbuf[(P) ^ 1][ul] = (_Float16)hval;                       \
    }                                                                          \
    if (w == 3) {                                                              \
      Xbuf[(P) ^ 1][lane] = (_Float16)xA;                                      \
      xA = xB;                                                                 \
      xB = xn;                                                                 \
    }                                                                          \
    __syncthreads();                                                           \
  }

  for (int s = 0; s < LSTM_S; s += 2) {
    STEPB(0, accP, accQ, X0a, X0b, X1a, X1b)
    ++s;
    STEPB(1, accQ, accP, X1a, X1b, X0a, X0b)
    --s;
  }
  #undef STEPB

  // ---- output: out[b] = h_last @ Wo + bo ----
  if (lane < 32) R[ul] = hval * Wo[ul];
  __syncthreads();
  if (t < 64) {
    float v = R[t] + R[t + 64];
    #pragma unroll
    for (int off = 32; off; off >>= 1) v += __shfl_down(v, off);
    if (t == 0) out[b] = v + bo[0];
  }
}

extern "C" void kernel_launch(void* const* d_in, const int* in_sizes, int n_in,
                              void* d_out, int out_size, void* d_ws, size_t ws_size,
                              hipStream_t stream) {
  const float* x  = (const float*)d_in[0];
  const float* Wi = (const float*)d_in[1];
  const float* Wh = (const float*)d_in[2];
  const float* bh = (const float*)d_in[3];
  const float* Wo = (const float*)d_in[4];
  const float* bo = (const float*)d_in[5];
  float* out = (float*)d_out;

  lstm_mfma_kernel<<<LSTM_B, 256, 0, stream>>>(x, Wi, Wh, bh, Wo, bo, out);
}